// Round 1
// baseline (380.284 us; speedup 1.0000x reference)
//
#include <hip/hip_runtime.h>

// BinarizeLinear: out[65536,1024] = x @ sign(W)^T + bias
// bf16 MFMA GEMM (16x16x32), 128x128 tile, BK=32, reg-staged with fused
// fp32->bf16 convert (x) and sign()->bf16 (W). Double-buffered LDS, early
// global-load issue (T14). Padded LDS stride 40 elems (16B-aligned rows,
// uniform bank spread for ds_read_b128).

typedef __bf16 bf16x8 __attribute__((ext_vector_type(8)));
typedef __bf16 bf16x4 __attribute__((ext_vector_type(4)));
typedef float  f32x4  __attribute__((ext_vector_type(4)));

constexpr int Mdim = 65536;
constexpr int Ndim = 1024;
constexpr int Kdim = 1024;
constexpr int BM = 128, BN = 128, BK = 32;
constexpr int BKP = 40;              // padded LDS row stride (elems) = 80B
constexpr int NT = Kdim / BK;        // 32 K-steps

__global__ __launch_bounds__(256)
void binlin_kernel(const float* __restrict__ X, const float* __restrict__ W,
                   const float* __restrict__ bias, float* __restrict__ out)
{
    __shared__ __align__(16) __bf16 Al[2][BM][BKP];
    __shared__ __align__(16) __bf16 Bl[2][BN][BKP];

    const int bid  = blockIdx.x;
    const int colb = bid & 7;          // N/BN = 8 column panels (fastest-varying
    const int rowb = bid >> 3;         // so concurrent blocks share the X row panel via L2/L3)
    const int row0 = rowb * BM;
    const int col0 = colb * BN;

    const int tid  = threadIdx.x;
    const int lane = tid & 63;
    const int wid  = tid >> 6;
    const int wr   = wid >> 1;         // 2x2 waves, each owns a 64x64 output sub-tile
    const int wc   = wid & 1;

    // staging: 256 threads cover a 128x32 f32 tile as 4 passes of (32 rows x 8 float4)
    const int sr = tid >> 3;           // 0..31 row within pass-slab
    const int sc = tid & 7;            // 0..7  float4 within row

    const float* Xb = X + (size_t)row0 * Kdim;
    const float* Wb = W + (size_t)col0 * Kdim;

    float4 ra[4], rb[4];

    auto GLOAD = [&](int k0) {
#pragma unroll
        for (int p = 0; p < 4; ++p) {
            const int r = p * 32 + sr;
            ra[p] = *(const float4*)(Xb + (size_t)r * Kdim + k0 + sc * 4);
            rb[p] = *(const float4*)(Wb + (size_t)r * Kdim + k0 + sc * 4);
        }
    };

    auto DSW = [&](int buf) {
#pragma unroll
        for (int p = 0; p < 4; ++p) {
            const int r = p * 32 + sr;
            bf16x4 va;
            va[0] = (__bf16)ra[p].x; va[1] = (__bf16)ra[p].y;
            va[2] = (__bf16)ra[p].z; va[3] = (__bf16)ra[p].w;
            *(bf16x4*)&Al[buf][r][sc * 4] = va;
            bf16x4 vb;
            vb[0] = (__bf16)(float)((rb[p].x > 0.f) - (rb[p].x < 0.f));
            vb[1] = (__bf16)(float)((rb[p].y > 0.f) - (rb[p].y < 0.f));
            vb[2] = (__bf16)(float)((rb[p].z > 0.f) - (rb[p].z < 0.f));
            vb[3] = (__bf16)(float)((rb[p].w > 0.f) - (rb[p].w < 0.f));
            *(bf16x4*)&Bl[buf][r][sc * 4] = vb;
        }
    };

    f32x4 acc[4][4] = {};

    const int fr  = lane & 15;          // fragment row/col within 16
    const int ks  = (lane >> 4) * 8;    // k-slice start (elems)
    const int ar0 = wr * 64 + fr;
    const int bc0 = wc * 64 + fr;

    auto COMP = [&](int buf) {
        bf16x8 af[4], bf[4];
#pragma unroll
        for (int i = 0; i < 4; ++i)
            af[i] = *(const bf16x8*)&Al[buf][ar0 + i * 16][ks];
#pragma unroll
        for (int j = 0; j < 4; ++j)
            bf[j] = *(const bf16x8*)&Bl[buf][bc0 + j * 16][ks];
#pragma unroll
        for (int i = 0; i < 4; ++i)
#pragma unroll
            for (int j = 0; j < 4; ++j)
                acc[i][j] = __builtin_amdgcn_mfma_f32_16x16x32_bf16(
                    af[i], bf[j], acc[i][j], 0, 0, 0);
    };

    // prologue
    GLOAD(0);
    DSW(0);
    __syncthreads();

    int cur = 0;
    for (int kt = 0; kt < NT; ++kt) {
        if (kt + 1 < NT) GLOAD((kt + 1) * BK);   // issue early, in flight during COMP
        COMP(cur);
        if (kt + 1 < NT) {
            DSW(cur ^ 1);                         // vmcnt waits land here
            __syncthreads();
            cur ^= 1;
        }
    }

    // epilogue: C[row = i*16 + (lane>>4)*4 + r][col = j*16 + (lane&15)]  (m89 layout)
    const int orow = row0 + wr * 64 + (lane >> 4) * 4;
    const int ocol = col0 + wc * 64 + fr;
#pragma unroll
    for (int j = 0; j < 4; ++j) {
        const float bv = bias[ocol + j * 16];
#pragma unroll
        for (int i = 0; i < 4; ++i) {
#pragma unroll
            for (int r = 0; r < 4; ++r) {
                out[(size_t)(orow + i * 16 + r) * Ndim + (ocol + j * 16)] =
                    acc[i][j][r] + bv;
            }
        }
    }
}

extern "C" void kernel_launch(void* const* d_in, const int* in_sizes, int n_in,
                              void* d_out, int out_size, void* d_ws, size_t ws_size,
                              hipStream_t stream) {
    const float* x  = (const float*)d_in[0];
    const float* w  = (const float*)d_in[1];
    const float* b  = (const float*)d_in[2];
    float* out      = (float*)d_out;

    dim3 grid((Mdim / BM) * (Ndim / BN));  // 512 x 8 = 4096 blocks
    binlin_kernel<<<grid, dim3(256), 0, stream>>>(x, w, b, out);
}

// Round 2
// 305.347 us; speedup vs baseline: 1.2454x; 1.2454x over previous
//
#include <hip/hip_runtime.h>

// BinarizeLinear: out[65536,1024] = x @ sign(W)^T + bias
// Round 2: prepass converts sign(W)->bf16 into d_ws (2 MB); GEMM stages W via
// global_load_lds (width 16), x via reg-staged fused fp32->bf16 convert with
// conflict-free ds_write mapping. 128x128 tile, BK=32, double-buffered LDS
// (32 KB), T3-min 2-phase (issue next-tile loads before COMP), XCD-bijective
// blockIdx swizzle (4096 % 8 == 0).

typedef __bf16 bf16x8 __attribute__((ext_vector_type(8)));
typedef __bf16 bf16x4 __attribute__((ext_vector_type(4)));
typedef float  f32x4  __attribute__((ext_vector_type(4)));

constexpr int Mdim = 65536;
constexpr int Ndim = 1024;
constexpr int Kdim = 1024;
constexpr int BM = 128, BN = 128, BK = 32;
constexpr int NT = Kdim / BK;   // 32 K-steps

typedef const __attribute__((address_space(1))) char ga_char;
typedef __attribute__((address_space(3))) char lds_char;

__device__ __forceinline__ void gload16(const void* g, void* l) {
    // stages 64 lanes x 16 B = 1024 B at wave-uniform LDS base (+lane*16)
    __builtin_amdgcn_global_load_lds((ga_char*)g, (lds_char*)l, 16, 0, 0);
}

// ---- prepass: W fp32 -> sign() bf16 ----
__global__ __launch_bounds__(256)
void wsign_kernel(const float* __restrict__ W, __bf16* __restrict__ Wb) {
    const int i = blockIdx.x * 256 + threadIdx.x;   // one float4 per thread
    float4 v = ((const float4*)W)[i];
    bf16x4 o;
    o[0] = (__bf16)(float)((v.x > 0.f) - (v.x < 0.f));
    o[1] = (__bf16)(float)((v.y > 0.f) - (v.y < 0.f));
    o[2] = (__bf16)(float)((v.z > 0.f) - (v.z < 0.f));
    o[3] = (__bf16)(float)((v.w > 0.f) - (v.w < 0.f));
    ((bf16x4*)Wb)[i] = o;
}

// ---- main GEMM ----
// PREW=true: W already bf16-sign in Wb, staged via global_load_lds.
// PREW=false: fallback, W fp32 reg-staged with inline sign (no ws needed).
template<bool PREW>
__global__ __launch_bounds__(256)
void binlin_mfma(const float* __restrict__ X, const float* __restrict__ Wf,
                 const __bf16* __restrict__ Wb, const float* __restrict__ bias,
                 float* __restrict__ out)
{
    __shared__ __align__(16) __bf16 Al[2][BM][BK];   // 2 x 8 KB
    __shared__ __align__(16) __bf16 Bl[2][BN][BK];   // 2 x 8 KB

    // XCD-bijective swizzle: nwg=4096, 4096%8==0 -> simple chunked form.
    // XCD x runs tile ids [x*512, (x+1)*512): 64 row panels x all 8 col panels,
    // col fastest -> x row panel reused from XCD-local L2.
    constexpr int NWG = (Mdim / BM) * (Ndim / BN);   // 4096
    const int swz  = (blockIdx.x & 7) * (NWG / 8) + (blockIdx.x >> 3);
    const int colb = swz & 7;
    const int rowb = swz >> 3;
    const int row0 = rowb * BM;
    const int col0 = colb * BN;

    const int tid  = threadIdx.x;
    const int lane = tid & 63;
    const int wid  = tid >> 6;
    const int wr   = wid >> 1;        // 2x2 waves -> 64x64 output sub-tile each
    const int wc   = wid & 1;

    // reg-staging mapping (conflict-free ds_write: wave covers 1024 contiguous
    // LDS bytes): thread t -> row p*64 + (t>>2), elem col (t&3)*8
    const int sr = tid >> 2;          // 0..63
    const int sc = (tid & 3) * 8;     // elem col

    const float* Xb = X + (size_t)row0 * Kdim;
    const float* Wfb = Wf + (size_t)col0 * Kdim;
    const __bf16* Wbb = Wb + (size_t)col0 * Kdim;

    f32x4 ra[2][2];                   // x staging regs [p][vec]
    f32x4 rb[2][2];                   // W staging regs (fallback path only)

    auto GLA = [&](int k0) {
#pragma unroll
        for (int p = 0; p < 2; ++p) {
            const float* src = Xb + (size_t)(p * 64 + sr) * Kdim + k0 + sc;
            ra[p][0] = *(const f32x4*)src;
            ra[p][1] = *(const f32x4*)(src + 4);
        }
    };
    auto DSWA = [&](int buf) {
#pragma unroll
        for (int p = 0; p < 2; ++p) {
            bf16x8 v;
#pragma unroll
            for (int e = 0; e < 4; ++e) {
                v[e]     = (__bf16)ra[p][0][e];
                v[e + 4] = (__bf16)ra[p][1][e];
            }
            *(bf16x8*)&Al[buf][p * 64 + sr][sc] = v;
        }
    };

    // W staging, gload_lds path: chunk c = wid + p*4 covers rows [c*16, c*16+16)
    // lane l -> row c*16 + (l>>2), elem col (l&3)*8  (matches linear LDS fill)
    auto STB = [&](int buf, int k0) {
#pragma unroll
        for (int p = 0; p < 2; ++p) {
            const int c = wid + p * 4;
            const __bf16* g = Wbb + (size_t)(c * 16 + (lane >> 2)) * Kdim
                            + k0 + (lane & 3) * 8;
            gload16(g, &Bl[buf][c * 16][0]);
        }
    };
    // W staging, fallback reg path
    auto GLB = [&](int k0) {
#pragma unroll
        for (int p = 0; p < 2; ++p) {
            const float* src = Wfb + (size_t)(p * 64 + sr) * Kdim + k0 + sc;
            rb[p][0] = *(const f32x4*)src;
            rb[p][1] = *(const f32x4*)(src + 4);
        }
    };
    auto DSWB = [&](int buf) {
#pragma unroll
        for (int p = 0; p < 2; ++p) {
            bf16x8 v;
#pragma unroll
            for (int e = 0; e < 4; ++e) {
                float a = rb[p][0][e], b = rb[p][1][e];
                v[e]     = (__bf16)(float)((a > 0.f) - (a < 0.f));
                v[e + 4] = (__bf16)(float)((b > 0.f) - (b < 0.f));
            }
            *(bf16x8*)&Bl[buf][p * 64 + sr][sc] = v;
        }
    };

    f32x4 acc[4][4] = {};
    const int fr = lane & 15;
    const int ks = (lane >> 4) * 8;
    const int ar0 = wr * 64 + fr;
    const int bc0 = wc * 64 + fr;

    auto COMP = [&](int buf) {
        bf16x8 af[4], bfr[4];
#pragma unroll
        for (int i = 0; i < 4; ++i)
            af[i] = *(const bf16x8*)&Al[buf][ar0 + i * 16][ks];
#pragma unroll
        for (int j = 0; j < 4; ++j)
            bfr[j] = *(const bf16x8*)&Bl[buf][bc0 + j * 16][ks];
#pragma unroll
        for (int i = 0; i < 4; ++i)
#pragma unroll
            for (int j = 0; j < 4; ++j)
                acc[i][j] = __builtin_amdgcn_mfma_f32_16x16x32_bf16(
                    af[i], bfr[j], acc[i][j], 0, 0, 0);
    };

    // prologue: stage tile 0 into buf 0
    GLA(0);
    if constexpr (PREW) STB(0, 0); else { GLB(0); DSWB(0); }
    DSWA(0);
    __syncthreads();                  // drains vmcnt (gload_lds) + lgkm

    int cur = 0;
    for (int t = 0; t < NT; ++t) {
        if (t + 1 < NT) {             // issue next-tile loads BEFORE compute
            GLA((t + 1) * BK);
            if constexpr (PREW) STB(cur ^ 1, (t + 1) * BK);
            else GLB((t + 1) * BK);
        }
        COMP(cur);
        if (t + 1 < NT) {             // write-late: lands after compute
            DSWA(cur ^ 1);
            if constexpr (!PREW) DSWB(cur ^ 1);
            __syncthreads();
            cur ^= 1;
        }
    }

    // epilogue: C[row = i*16 + (lane>>4)*4 + r][col = j*16 + (lane&15)]
    const int orow = row0 + wr * 64 + (lane >> 4) * 4;
    const int ocol = col0 + wc * 64 + fr;
#pragma unroll
    for (int j = 0; j < 4; ++j) {
        const float bv = bias[ocol + j * 16];
#pragma unroll
        for (int i = 0; i < 4; ++i) {
#pragma unroll
            for (int r = 0; r < 4; ++r) {
                out[(size_t)(orow + i * 16 + r) * Ndim + (ocol + j * 16)] =
                    acc[i][j][r] + bv;
            }
        }
    }
}

extern "C" void kernel_launch(void* const* d_in, const int* in_sizes, int n_in,
                              void* d_out, int out_size, void* d_ws, size_t ws_size,
                              hipStream_t stream) {
    const float* x  = (const float*)d_in[0];
    const float* w  = (const float*)d_in[1];
    const float* b  = (const float*)d_in[2];
    float* out      = (float*)d_out;

    constexpr size_t WB_BYTES = (size_t)Ndim * Kdim * sizeof(__bf16);  // 2 MB
    dim3 grid((Mdim / BM) * (Ndim / BN));   // 4096 blocks

    if (ws_size >= WB_BYTES) {
        __bf16* wb = (__bf16*)d_ws;
        wsign_kernel<<<dim3(Ndim * Kdim / 4 / 256), dim3(256), 0, stream>>>(w, wb);
        binlin_mfma<true><<<grid, dim3(256), 0, stream>>>(x, w, wb, b, out);
    } else {
        binlin_mfma<false><<<grid, dim3(256), 0, stream>>>(x, w, (const __bf16*)w, b, out);
    }
}